// Round 6
// baseline (254.434 us; speedup 1.0000x reference)
//
#include <hip/hip_runtime.h>
#include <hip/hip_cooperative_groups.h>

namespace cg = cooperative_groups;

// DiscriminativeLoss: data [32, 512, 1024] f32 (D-planar), labels [512,1024] i32 in [0,16)
// out: scalar f32 loss.
//
// Lessons:
//  - LDS float atomicAdd ~300 cyc/wave-instr on gfx950 -> never in hot loop.
//  - Harness reset (268 MB ws fill ~42us + d_in restore ~21us) is in the timed window:
//    ~70us fixed floor. Rounds 4/5: LDS-layout + occupancy tweaks neutral -> bodies are
//    memory-bound already; remaining cost is launch gaps + redundant center reduction.
//  - This round: single cooperative kernel, grid.sync() between passes.
//
// ws float layout:
//   partials[chunk][k*32 + d] : [0, 8192)      ([chunk][slot] -> coalesced phase-2 reads)
//   cpart[chunk][k]           : [8192, 8448)

constexpr int KC = 16;
constexpr int DD = 32;
constexpr int NN = 512 * 1024;
constexpr int N4 = NN / 4;                        // 131072 float4 groups per d-plane
constexpr int CHUNKS = 16;
constexpr int GPC = N4 / CHUNKS;                  // 8192 groups per chunk
constexpr int ITERS = GPC / 256;                  // 32
constexpr int NBLK = 512;                         // 2 blocks/CU -> co-resident (cooperative)

__global__ __launch_bounds__(256) void kfused(const float4* __restrict__ data4,
                                              const int4* __restrict__ lab4,
                                              float* __restrict__ ws,
                                              float* __restrict__ out) {
    const int tid = threadIdx.x;
    const int bid = blockIdx.x;
    const int chunk = bid & 15;                   // 16 chunks
    const int d = bid >> 4;                       // 32 d-planes
    const bool doCnt = (d == 0);

    if (bid == 0 && tid == 0) out[0] = 0.f;       // visible to all after grid.sync

    // ---------------- Phase 1: per-cluster partial sums ----------------
    // acc[k*256 + tid]: bank = tid%32 independent of label -> deterministic 2-way (free).
    __shared__ float acc[KC * 256];
    __shared__ float cnt[KC * 256];
    __shared__ float csum[512];
    __shared__ float ccnt[KC];
    __shared__ float ct2[DD * 32];                // centers_t duplicated (k, k+16)
    __shared__ float red[256];
    __shared__ float wred[4];

#pragma unroll
    for (int k = 0; k < KC; ++k) acc[k * 256 + tid] = 0.f;
    if (doCnt) {
#pragma unroll
        for (int k = 0; k < KC; ++k) cnt[k * 256 + tid] = 0.f;
    }

    const float4* dplane = data4 + (size_t)d * N4;
    int g = chunk * GPC + tid;

    float4 v = dplane[g];
    int4 lb = lab4[g];
    for (int it = 0; it < ITERS; ++it) {
        float4 vn;
        int4 lbn;
        if (it + 1 < ITERS) {
            vn = dplane[g + 256];
            lbn = lab4[g + 256];
        }
        acc[lb.x * 256 + tid] += v.x;
        acc[lb.y * 256 + tid] += v.y;
        acc[lb.z * 256 + tid] += v.z;
        acc[lb.w * 256 + tid] += v.w;
        if (doCnt) {
            cnt[lb.x * 256 + tid] += 1.f;
            cnt[lb.y * 256 + tid] += 1.f;
            cnt[lb.z * 256 + tid] += 1.f;
            cnt[lb.w * 256 + tid] += 1.f;
        }
        v = vn;
        lb = lbn;
        g += 256;
    }
    __syncthreads();

    // Epilogue: thread t -> cluster k = t>>4, segment seg = t&15.
    {
        const int k = tid >> 4, seg = tid & 15;
        float s = 0.f;
#pragma unroll
        for (int i = 0; i < 16; ++i) s += acc[k * 256 + seg * 16 + i];
#pragma unroll
        for (int off = 8; off > 0; off >>= 1) s += __shfl_down(s, off, 16);
        if (seg == 0) ws[chunk * 512 + k * DD + d] = s;           // plain store
        if (doCnt) {
            float c = 0.f;
#pragma unroll
            for (int i = 0; i < 16; ++i) c += cnt[k * 256 + seg * 16 + i];
#pragma unroll
            for (int off = 8; off > 0; off >>= 1) c += __shfl_down(c, off, 16);
            if (seg == 0) ws[8192 + chunk * 16 + k] = c;          // plain store
        }
    }

    __threadfence();                              // release partials device-wide
    cg::this_grid().sync();                       // cross-XCD barrier
    __threadfence();                              // acquire

    // ---------------- Phase 2a: centers (redundant per block, coalesced) ----------------
    if (tid < KC) {
        float c = 0.f;
#pragma unroll
        for (int i = 0; i < CHUNKS; ++i) c += ws[8192 + i * 16 + tid];
        ccnt[tid] = c;
    }
    for (int idx = tid; idx < 512; idx += 256) {
        float s = 0.f;
#pragma unroll
        for (int cch = 0; cch < CHUNKS; ++cch) s += ws[cch * 512 + idx];  // coalesced
        csum[idx] = s;
    }
    __syncthreads();
    for (int idx = tid; idx < KC * DD; idx += 256) {
        const int k = idx >> 5, dd = idx & 31;
        const float c = csum[k * 32 + dd] / ccnt[k];
        ct2[dd * 32 + k] = c;
        ct2[dd * 32 + 16 + k] = c;
    }
    __syncthreads();

    // ---------------- Phase 2b: dist + reg terms (block 0 only) ----------------
    if (bid == 0) {
        const int i = tid >> 4, j = tid & 15;
        float val;
        if (i != j) {
            float sq = 0.f;
#pragma unroll
            for (int dd = 0; dd < DD; ++dd) {
                const float df = ct2[dd * 32 + i] - ct2[dd * 32 + j];
                sq += df * df;
            }
            const float pd = sqrtf(sq);
            const float t = fmaxf(3.0f - pd, 0.f);               // 2*DELTA_DIST
            val = t * t * (1.0f / (KC * (KC - 1)));
        } else {
            float s2 = 0.f;
#pragma unroll
            for (int dd = 0; dd < DD; ++dd) s2 += ct2[dd * 32 + i] * ct2[dd * 32 + i];
            val = sqrtf(s2) * (0.001f / KC);                      // reg term
        }
        red[tid] = val;
        __syncthreads();
        for (int off = 128; off > 0; off >>= 1) {
            if (tid < off) red[tid] += red[tid + off];
            __syncthreads();
        }
        if (tid == 0) atomicAdd(out, red[0]);
    }

    // ---------------- Phase 2c: variance term ----------------
    g = bid * 256 + tid;                          // 512*256 = N4 float4 groups
    lb = lab4[g];
    const int dup = (tid & 32) >> 1;              // lanes 32-63 use the +16 duplicate
    const int o0 = lb.x + dup, o1 = lb.y + dup, o2 = lb.z + dup, o3 = lb.w + dup;

    float s0 = 0.f, s1 = 0.f, s2 = 0.f, s3 = 0.f;
#pragma unroll 8
    for (int dd = 0; dd < DD; ++dd) {
        const float4 vv = data4[(size_t)dd * N4 + g];
        const float* ctd = ct2 + dd * 32;
        const float d0 = ctd[o0] - vv.x; s0 += d0 * d0;
        const float d1 = ctd[o1] - vv.y; s1 += d1 * d1;
        const float d2 = ctd[o2] - vv.z; s2 += d2 * d2;
        const float d3 = ctd[o3] - vv.w; s3 += d3 * d3;
    }
    const float h0 = fmaxf(sqrtf(s0) - 0.5f, 0.f);
    const float h1 = fmaxf(sqrtf(s1) - 0.5f, 0.f);
    const float h2 = fmaxf(sqrtf(s2) - 0.5f, 0.f);
    const float h3 = fmaxf(sqrtf(s3) - 0.5f, 0.f);
    float lsum = h0 * h0 + h1 * h1 + h2 * h2 + h3 * h3;

#pragma unroll
    for (int off = 32; off > 0; off >>= 1) lsum += __shfl_down(lsum, off);
    if ((tid & 63) == 0) wred[tid >> 6] = lsum;
    __syncthreads();
    if (tid == 0) {
        const float s = wred[0] + wred[1] + wred[2] + wred[3];
        atomicAdd(out, s * (1.0f / KC));
    }
}

extern "C" void kernel_launch(void* const* d_in, const int* in_sizes, int n_in,
                              void* d_out, int out_size, void* d_ws, size_t ws_size,
                              hipStream_t stream) {
    const float4* data4 = (const float4*)d_in[0];
    const int4* lab4 = (const int4*)d_in[1];
    float* out = (float*)d_out;
    float* ws = (float*)d_ws;

    void* args[] = {(void*)&data4, (void*)&lab4, (void*)&ws, (void*)&out};
    hipLaunchCooperativeKernel((const void*)kfused, dim3(NBLK), dim3(256), args, 0, stream);
}

// Round 7
// 183.143 us; speedup vs baseline: 1.3893x; 1.3893x over previous
//
#include <hip/hip_runtime.h>

// DiscriminativeLoss: data [32, 512, 1024] f32 (D-planar), labels [512,1024] i32 in [0,16)
// out: scalar f32 loss.
//
// ROUND 7 = MEASUREMENT ROUND. Round-4 kernels (best: 119.0us) with in-kernel repeats
// (kA x4, kB x5, idempotent; atomics only on rep 0) so each dispatch exceeds the ~42us
// harness-fill band and surfaces in rocprof top-5 with its own counters. dur_us will
// regress (~180); buys per-kernel dur/FETCH/VALUBusy/conflicts/occupancy to locate the
// ~20us unexplained vs the memory-floor model.
//
// Lessons so far:
//  - LDS float atomicAdd ~300 cyc/wave-instr on gfx950 -> never in hot loop.
//  - grid.sync() cooperative path: ~150us of stall for this op -> dead. Kernel boundary
//    is the cheap global barrier.
//  - Harness reset (268 MB ws fill ~42us + d_in restore ~21us) is fixed ~70us in-window.
//
// ws float layout:
//   partials[(k*32 + d)*32 + chunk] : [0, 16384)
//   cpart[k*32 + chunk]             : [16384, 16896)

constexpr int KC = 16;
constexpr int DD = 32;
constexpr int NN = 512 * 1024;
constexpr int N4 = NN / 4;                        // 131072 float4 groups per d-plane
constexpr int CHUNKS = 32;
constexpr int GROUPS_PER_CHUNK = N4 / CHUNKS;     // 4096
constexpr int K1_ITERS = GROUPS_PER_CHUNK / 256;  // 16

constexpr int WS_P  = 0;
constexpr int WS_CP = 16384;

constexpr int REPS_A = 4;
constexpr int REPS_B = 5;

__global__ __launch_bounds__(256) void kA_sums(const float4* __restrict__ data4,
                                               const int4* __restrict__ lab4,
                                               float* __restrict__ ws,
                                               float* __restrict__ out) {
    const int tid = threadIdx.x;
    const int chunk = blockIdx.x;
    const int d = blockIdx.y;
    const bool doCnt = (d == 0);

    if (chunk == 0 && d == 0 && tid == 0) out[0] = 0.f;  // kB atomicAdds on top

    __shared__ float acc[256 * 17];
    __shared__ float cnt[256 * 17];
    float* arow = acc + tid * 17;
    float* crow = cnt + tid * 17;

    for (int rep = 0; rep < REPS_A; ++rep) {
#pragma unroll
        for (int k = 0; k < KC; ++k) arow[k] = 0.f;
        if (doCnt) {
#pragma unroll
            for (int k = 0; k < KC; ++k) crow[k] = 0.f;
        }

        const int base = chunk * GROUPS_PER_CHUNK + tid;
        const float4* dplane = data4 + (size_t)d * N4;

        for (int it = 0; it < K1_ITERS; ++it) {
            const int g = base + it * 256;
            const float4 v = dplane[g];
            const int4 lb = lab4[g];
            arow[lb.x] += v.x;
            arow[lb.y] += v.y;
            arow[lb.z] += v.z;
            arow[lb.w] += v.w;
            if (doCnt) {
                crow[lb.x] += 1.f;
                crow[lb.y] += 1.f;
                crow[lb.z] += 1.f;
                crow[lb.w] += 1.f;
            }
        }
        __syncthreads();

        // Transposed epilogue: thread t -> cluster k = t>>4, segment seg = t&15.
        const int k = tid >> 4, seg = tid & 15;
        float s = 0.f;
#pragma unroll
        for (int i = 0; i < 16; ++i) s += acc[(seg * 16 + i) * 17 + k];
#pragma unroll
        for (int off = 8; off > 0; off >>= 1) s += __shfl_down(s, off, 16);
        if (seg == 0) ws[WS_P + (k * DD + d) * CHUNKS + chunk] = s;   // idempotent store
        if (doCnt) {
            float c = 0.f;
#pragma unroll
            for (int i = 0; i < 16; ++i) c += cnt[(seg * 16 + i) * 17 + k];
#pragma unroll
            for (int off = 8; off > 0; off >>= 1) c += __shfl_down(c, off, 16);
            if (seg == 0) ws[WS_CP + k * CHUNKS + chunk] = c;         // idempotent store
        }
        __syncthreads();   // epilogue reads all rows; protect re-zero of next rep
    }
}

__global__ __launch_bounds__(256) void kB_var(const float4* __restrict__ data4,
                                              const int4* __restrict__ lab4,
                                              const float* __restrict__ ws,
                                              float* __restrict__ out) {
    __shared__ float csum[KC * 33];
    __shared__ float ccnt[KC];
    __shared__ float ct2[DD * 32];       // centers_t duplicated (k, k+16)
    __shared__ float red[256];
    __shared__ float wred[4];
    const int tid = threadIdx.x;

    for (int rep = 0; rep < REPS_B; ++rep) {
        // Redundant per-block center build (L2-resident partials, 66 KB).
        {
            int idx = tid;
            const float* p = ws + WS_P + idx * CHUNKS;
            float s = 0.f;
#pragma unroll
            for (int c = 0; c < CHUNKS; ++c) s += p[c];
            csum[(idx >> 5) * 33 + (idx & 31)] = s;
            idx = tid + 256;
            p = ws + WS_P + idx * CHUNKS;
            s = 0.f;
#pragma unroll
            for (int c = 0; c < CHUNKS; ++c) s += p[c];
            csum[(idx >> 5) * 33 + (idx & 31)] = s;
        }
        if (tid < KC) {
            const float* p = ws + WS_CP + tid * CHUNKS;
            float c = 0.f;
#pragma unroll
            for (int i = 0; i < CHUNKS; ++i) c += p[i];
            ccnt[tid] = c;
        }
        __syncthreads();

        for (int idx = tid; idx < KC * DD; idx += 256) {
            const int k = idx >> 5, d = idx & 31;
            const float c = csum[k * 33 + d] / ccnt[k];
            ct2[d * 32 + k] = c;
            ct2[d * 32 + 16 + k] = c;
        }
        __syncthreads();

        // Dist + reg terms: block 0, first rep only.
        if (blockIdx.x == 0 && rep == 0) {
            const int i = tid >> 4, j = tid & 15;
            float val;
            if (i != j) {
                float sq = 0.f;
#pragma unroll
                for (int d = 0; d < DD; ++d) {
                    const float df = ct2[d * 32 + i] - ct2[d * 32 + j];
                    sq += df * df;
                }
                const float pd = sqrtf(sq);
                const float t = fmaxf(3.0f - pd, 0.f);            // 2*DELTA_DIST
                val = t * t * (1.0f / (KC * (KC - 1)));
            } else {
                float s2 = 0.f;
#pragma unroll
                for (int d = 0; d < DD; ++d) s2 += ct2[d * 32 + i] * ct2[d * 32 + i];
                val = sqrtf(s2) * (0.001f / KC);                   // reg term
            }
            red[tid] = val;
            __syncthreads();
            for (int off = 128; off > 0; off >>= 1) {
                if (tid < off) red[tid] += red[tid + off];
                __syncthreads();
            }
            if (tid == 0) atomicAdd(out, red[0]);
        }

        // Pass 2: one float4 group per thread (512 blocks x 256 = N4).
        const int g = blockIdx.x * 256 + tid;
        const int4 lb = lab4[g];
        const int dup = (tid & 32) >> 1;
        const int o0 = lb.x + dup, o1 = lb.y + dup, o2 = lb.z + dup, o3 = lb.w + dup;

        float s0 = 0.f, s1 = 0.f, s2 = 0.f, s3 = 0.f;
#pragma unroll 8
        for (int d = 0; d < DD; ++d) {
            const float4 v = data4[(size_t)d * N4 + g];
            const float* ctd = ct2 + d * 32;
            const float d0 = ctd[o0] - v.x; s0 += d0 * d0;
            const float d1 = ctd[o1] - v.y; s1 += d1 * d1;
            const float d2 = ctd[o2] - v.z; s2 += d2 * d2;
            const float d3 = ctd[o3] - v.w; s3 += d3 * d3;
        }
        const float h0 = fmaxf(sqrtf(s0) - 0.5f, 0.f);
        const float h1 = fmaxf(sqrtf(s1) - 0.5f, 0.f);
        const float h2 = fmaxf(sqrtf(s2) - 0.5f, 0.f);
        const float h3 = fmaxf(sqrtf(s3) - 0.5f, 0.f);
        float lsum = h0 * h0 + h1 * h1 + h2 * h2 + h3 * h3;

#pragma unroll
        for (int off = 32; off > 0; off >>= 1) lsum += __shfl_down(lsum, off);
        if ((tid & 63) == 0) wred[tid >> 6] = lsum;
        __syncthreads();
        if (tid == 0 && rep == 0) {
            const float s = wred[0] + wred[1] + wred[2] + wred[3];
            atomicAdd(out, s * (1.0f / KC));
        }
        __syncthreads();   // protect csum/ct2/wred rewrite next rep
    }
}

extern "C" void kernel_launch(void* const* d_in, const int* in_sizes, int n_in,
                              void* d_out, int out_size, void* d_ws, size_t ws_size,
                              hipStream_t stream) {
    const float4* data4 = (const float4*)d_in[0];
    const int4* lab4 = (const int4*)d_in[1];
    float* out = (float*)d_out;
    float* ws = (float*)d_ws;

    kA_sums<<<dim3(CHUNKS, DD), 256, 0, stream>>>(data4, lab4, ws, out);
    kB_var<<<512, 256, 0, stream>>>(data4, lab4, ws, out);
}

// Round 8
// 111.937 us; speedup vs baseline: 2.2730x; 1.6361x over previous
//
#include <hip/hip_runtime.h>

// DiscriminativeLoss: data [32, 512, 1024] f32 (D-planar), labels [512,1024] i32 in [0,16)
// out: scalar f32 loss.
//
// Lessons:
//  - LDS float atomicAdd ~300 cyc/wave-instr on gfx950 -> never in hot loop.
//  - grid.sync() cooperative: ~150us stall -> dead. Kernel boundary is the cheap barrier.
//  - Harness reset (268 MB ws fill + d_in restore) ~72us fixed inside the timed window.
//  - Round 7 measurement: kB = 11.7us/rep, L3-fed (hbm_bytes~0), at per-CU vmem cap -> done.
//    kA cold ~28us vs 10.5us HBM floor: the 4 LDS RMWs may alias (lb.x==lb.y possible) ->
//    compiler serializes 4x ~125cyc LDS round trips per iter.
//  - THIS ROUND: column-rotation no-alias accumulators: component c -> column (t+64c)&255.
//    Residues mod 256 pairwise distinct -> reads hoistable by construction; one LDS
//    latency per iter, not four. Bank = tid%32 (2-way, free) preserved.
//
// ws float layout:
//   partials[(k*32 + d)*32 + chunk] : [0, 16384)
//   cpart[k*32 + chunk]             : [16384, 16896)

constexpr int KC = 16;
constexpr int DD = 32;
constexpr int NN = 512 * 1024;
constexpr int N4 = NN / 4;                        // 131072 float4 groups per d-plane
constexpr int CHUNKS = 32;
constexpr int GROUPS_PER_CHUNK = N4 / CHUNKS;     // 4096
constexpr int K1_ITERS = GROUPS_PER_CHUNK / 256;  // 16

constexpr int WS_P  = 0;
constexpr int WS_CP = 16384;

__global__ __launch_bounds__(256) void kA_sums(const float4* __restrict__ data4,
                                               const int4* __restrict__ lab4,
                                               float* __restrict__ ws,
                                               float* __restrict__ out) {
    const int tid = threadIdx.x;
    const int chunk = blockIdx.x;
    const int d = blockIdx.y;
    const bool doCnt = (d == 0);

    if (chunk == 0 && d == 0 && tid == 0) out[0] = 0.f;  // kB atomicAdds on top

    // acc[k*256 + col]: component c of thread t uses col (t+64c)&255 -> the 4 RMW
    // targets are pairwise distinct mod 256 for ANY labels -> no aliasing, reads
    // hoisted below. Bank = col%32 = tid%32 -> deterministic 2-way (free).
    __shared__ float acc[KC * 256];
    __shared__ float cnt[KC * 256];
#pragma unroll
    for (int k = 0; k < KC; ++k) acc[k * 256 + tid] = 0.f;
    if (doCnt) {
#pragma unroll
        for (int k = 0; k < KC; ++k) cnt[k * 256 + tid] = 0.f;
    }
    __syncthreads();

    const int c0 = tid;
    const int c1 = (tid + 64) & 255;
    const int c2 = (tid + 128) & 255;
    const int c3 = (tid + 192) & 255;

    const float4* dplane = data4 + (size_t)d * N4;
    int g = chunk * GROUPS_PER_CHUNK + tid;

    // 1-deep register prefetch: next global loads overlap current LDS work.
    float4 v = dplane[g];
    int4 lb = lab4[g];
    for (int it = 0; it < K1_ITERS; ++it) {
        float4 vn;
        int4 lbn;
        if (it + 1 < K1_ITERS) {
            vn = dplane[g + 256];
            lbn = lab4[g + 256];
        }
        const int i0 = lb.x * 256 + c0;
        const int i1 = lb.y * 256 + c1;
        const int i2 = lb.z * 256 + c2;
        const int i3 = lb.w * 256 + c3;
        // Hoisted reads: i0..i3 provably distinct -> 4 independent ds_read, 1 wait.
        const float a0 = acc[i0];
        const float a1 = acc[i1];
        const float a2 = acc[i2];
        const float a3 = acc[i3];
        acc[i0] = a0 + v.x;
        acc[i1] = a1 + v.y;
        acc[i2] = a2 + v.z;
        acc[i3] = a3 + v.w;
        if (doCnt) {
            const float b0 = cnt[i0];
            const float b1 = cnt[i1];
            const float b2 = cnt[i2];
            const float b3 = cnt[i3];
            cnt[i0] = b0 + 1.f;
            cnt[i1] = b1 + 1.f;
            cnt[i2] = b2 + 1.f;
            cnt[i3] = b3 + 1.f;
        }
        v = vn;
        lb = lbn;
        g += 256;
    }
    __syncthreads();

    // Epilogue: thread t -> cluster k = t>>4, segment seg = t&15 (16 columns each).
    const int k = tid >> 4, seg = tid & 15;
    float s = 0.f;
#pragma unroll
    for (int i = 0; i < 16; ++i) s += acc[k * 256 + seg * 16 + i];
#pragma unroll
    for (int off = 8; off > 0; off >>= 1) s += __shfl_down(s, off, 16);
    if (seg == 0) ws[WS_P + (k * DD + d) * CHUNKS + chunk] = s;   // plain store
    if (doCnt) {
        float c = 0.f;
#pragma unroll
        for (int i = 0; i < 16; ++i) c += cnt[k * 256 + seg * 16 + i];
#pragma unroll
        for (int off = 8; off > 0; off >>= 1) c += __shfl_down(c, off, 16);
        if (seg == 0) ws[WS_CP + k * CHUNKS + chunk] = c;         // plain store
    }
}

__global__ __launch_bounds__(256) void kB_var(const float4* __restrict__ data4,
                                              const int4* __restrict__ lab4,
                                              const float* __restrict__ ws,
                                              float* __restrict__ out) {
    __shared__ float csum[KC * 33];
    __shared__ float ccnt[KC];
    __shared__ float ct2[DD * 32];       // centers_t duplicated (k, k+16)
    const int tid = threadIdx.x;

    // Redundant per-block center build (partials are L2/L3-resident, 66 KB).
    {
        int idx = tid;
        const float* p = ws + WS_P + idx * CHUNKS;
        float s = 0.f;
#pragma unroll
        for (int c = 0; c < CHUNKS; ++c) s += p[c];
        csum[(idx >> 5) * 33 + (idx & 31)] = s;
        idx = tid + 256;
        p = ws + WS_P + idx * CHUNKS;
        s = 0.f;
#pragma unroll
        for (int c = 0; c < CHUNKS; ++c) s += p[c];
        csum[(idx >> 5) * 33 + (idx & 31)] = s;
    }
    if (tid < KC) {
        const float* p = ws + WS_CP + tid * CHUNKS;
        float c = 0.f;
#pragma unroll
        for (int i = 0; i < CHUNKS; ++i) c += p[i];
        ccnt[tid] = c;
    }
    __syncthreads();

    for (int idx = tid; idx < KC * DD; idx += 256) {
        const int k = idx >> 5, d = idx & 31;
        const float c = csum[k * 33 + d] / ccnt[k];
        ct2[d * 32 + k] = c;
        ct2[d * 32 + 16 + k] = c;
    }
    __syncthreads();

    // Dist + reg terms: block 0 only.
    if (blockIdx.x == 0) {
        const int i = tid >> 4, j = tid & 15;
        float val;
        if (i != j) {
            float sq = 0.f;
#pragma unroll
            for (int d = 0; d < DD; ++d) {
                const float df = ct2[d * 32 + i] - ct2[d * 32 + j];
                sq += df * df;
            }
            const float pd = sqrtf(sq);
            const float t = fmaxf(3.0f - pd, 0.f);            // 2*DELTA_DIST
            val = t * t * (1.0f / (KC * (KC - 1)));
        } else {
            float s2 = 0.f;
#pragma unroll
            for (int d = 0; d < DD; ++d) s2 += ct2[d * 32 + i] * ct2[d * 32 + i];
            val = sqrtf(s2) * (0.001f / KC);                   // reg term
        }
        __shared__ float red[256];
        red[tid] = val;
        __syncthreads();
        for (int off = 128; off > 0; off >>= 1) {
            if (tid < off) red[tid] += red[tid + off];
            __syncthreads();
        }
        if (tid == 0) atomicAdd(out, red[0]);
        __syncthreads();
    }

    // Pass 2: one float4 group per thread (512 blocks x 256 = N4). L3-fed, ~11.7us.
    const int g = blockIdx.x * 256 + tid;
    const int4 lb = lab4[g];
    const int dup = (tid & 32) >> 1;     // lanes 32-63 read the +16 duplicate
    const int o0 = lb.x + dup, o1 = lb.y + dup, o2 = lb.z + dup, o3 = lb.w + dup;

    float s0 = 0.f, s1 = 0.f, s2 = 0.f, s3 = 0.f;
#pragma unroll 8
    for (int d = 0; d < DD; ++d) {
        const float4 v = data4[(size_t)d * N4 + g];
        const float* ctd = ct2 + d * 32;
        const float d0 = ctd[o0] - v.x; s0 += d0 * d0;
        const float d1 = ctd[o1] - v.y; s1 += d1 * d1;
        const float d2 = ctd[o2] - v.z; s2 += d2 * d2;
        const float d3 = ctd[o3] - v.w; s3 += d3 * d3;
    }
    const float h0 = fmaxf(sqrtf(s0) - 0.5f, 0.f);
    const float h1 = fmaxf(sqrtf(s1) - 0.5f, 0.f);
    const float h2 = fmaxf(sqrtf(s2) - 0.5f, 0.f);
    const float h3 = fmaxf(sqrtf(s3) - 0.5f, 0.f);
    float lsum = h0 * h0 + h1 * h1 + h2 * h2 + h3 * h3;

#pragma unroll
    for (int off = 32; off > 0; off >>= 1) lsum += __shfl_down(lsum, off);
    __shared__ float wred[4];
    if ((tid & 63) == 0) wred[tid >> 6] = lsum;
    __syncthreads();
    if (tid == 0) {
        const float s = wred[0] + wred[1] + wred[2] + wred[3];
        atomicAdd(out, s * (1.0f / KC));
    }
}

extern "C" void kernel_launch(void* const* d_in, const int* in_sizes, int n_in,
                              void* d_out, int out_size, void* d_ws, size_t ws_size,
                              hipStream_t stream) {
    const float4* data4 = (const float4*)d_in[0];
    const int4* lab4 = (const int4*)d_in[1];
    float* out = (float*)d_out;
    float* ws = (float*)d_ws;

    kA_sums<<<dim3(CHUNKS, DD), 256, 0, stream>>>(data4, lab4, ws, out);
    kB_var<<<512, 256, 0, stream>>>(data4, lab4, ws, out);
}